// Round 1
// baseline (460.464 us; speedup 1.0000x reference)
//
#include <hip/hip_runtime.h>

#define NB 16
#define CIN 512
#define HH 32
#define WW 32
#define DD 64
#define KK 8192
#define OUTC 512
#define NROWS (NB * HH * WW)          // 16384
#define OUT_MAIN (NB * OUTC * HH * WW) // 8388608

// ---------------- K1: encoder 1x1 conv: z[n][d] = x[b,:,h,w]·w_in[d,:] + b_in[d]
__global__ __launch_bounds__(256) void k_enc(const float* __restrict__ x,
                                             const float* __restrict__ w_in,
                                             const float* __restrict__ b_in,
                                             float* __restrict__ zf) {
  __shared__ float Wt[128][68];  // [c][d], pad 68 keeps 16B align + fewer bank conflicts
  const int bh = blockIdx.x;     // b*32 + h
  const int b = bh >> 5, h = bh & 31;
  const int t = threadIdx.x;
  const int w = t & 31, dg = t >> 5;  // dg in [0,8)
  float acc[8];
#pragma unroll
  for (int j = 0; j < 8; ++j) acc[j] = b_in[dg * 8 + j];
  const float* xb = x + ((size_t)b * CIN * (HH * WW)) + h * WW + w;
  for (int c0 = 0; c0 < CIN; c0 += 128) {
    __syncthreads();
#pragma unroll
    for (int i = 0; i < 32; ++i) {
      int e = t + 256 * i;
      int cc = e & 127, d = e >> 7;
      Wt[cc][d] = w_in[d * CIN + c0 + cc];
    }
    __syncthreads();
#pragma unroll 4
    for (int c = 0; c < 128; ++c) {
      float xv = xb[(size_t)(c0 + c) * (HH * WW)];
      const float4 w0 = *(const float4*)&Wt[c][dg * 8];
      const float4 w1 = *(const float4*)&Wt[c][dg * 8 + 4];
      acc[0] = fmaf(xv, w0.x, acc[0]);
      acc[1] = fmaf(xv, w0.y, acc[1]);
      acc[2] = fmaf(xv, w0.z, acc[2]);
      acc[3] = fmaf(xv, w0.w, acc[3]);
      acc[4] = fmaf(xv, w1.x, acc[4]);
      acc[5] = fmaf(xv, w1.y, acc[5]);
      acc[6] = fmaf(xv, w1.z, acc[6]);
      acc[7] = fmaf(xv, w1.w, acc[7]);
    }
  }
  float* zr = zf + ((size_t)(bh * 32 + w)) * DD + dg * 8;
#pragma unroll
  for (int j = 0; j < 8; ++j) zr[j] = acc[j];
}

// ---------------- K2: e2[k] = ||emb[k]||^2
__global__ __launch_bounds__(256) void k_e2(const float* __restrict__ emb,
                                            float* __restrict__ e2) {
  int k = blockIdx.x * 256 + threadIdx.x;
  const float4* er = (const float4*)(emb + (size_t)k * DD);
  float s = 0.f;
#pragma unroll
  for (int i = 0; i < 16; ++i) {
    float4 v = er[i];
    s = fmaf(v.x, v.x, s);
    s = fmaf(v.y, v.y, s);
    s = fmaf(v.z, v.z, s);
    s = fmaf(v.w, v.w, s);
  }
  e2[k] = s;
}

// ---------------- K3: fused distance-GEMM + argmin (k-split in 2 halves)
__global__ __launch_bounds__(256) void k_argmin(const float* __restrict__ zf,
                                                const float* __restrict__ emb,
                                                const float* __restrict__ e2,
                                                float* __restrict__ pminv,
                                                int* __restrict__ pidx) {
  __shared__ float Zt[64][68];  // [d][row]
  __shared__ float Et[64][68];  // [d][k]
  __shared__ float e2t[64];
  const int bx = blockIdx.x;
  const int rt = bx >> 1, kh = bx & 1;
  const int r0 = rt * 64;
  const int t = threadIdx.x;
  const int tx = t & 15, ty = t >> 4;  // thread computes rows ty*4..+4 x ks tx*4..+4
  const int ds = t & 63, rs = t >> 6;  // staging coords
#pragma unroll
  for (int i = 0; i < 16; ++i) {
    int r = rs + 4 * i;
    Zt[ds][r] = zf[(size_t)(r0 + r) * DD + ds];
  }
  float mv[4];
  int mi[4];
#pragma unroll
  for (int i = 0; i < 4; ++i) { mv[i] = 3.4e38f; mi[i] = 0; }
  for (int kt = 0; kt < 64; ++kt) {
    const int k0 = kh * 4096 + kt * 64;
    __syncthreads();  // Z staged (kt==0) / previous tile consumed
#pragma unroll
    for (int i = 0; i < 16; ++i) {
      int kk = rs + 4 * i;
      Et[ds][kk] = emb[(size_t)(k0 + kk) * DD + ds];
    }
    if (t < 64) e2t[t] = e2[k0 + t];
    __syncthreads();
    float acc[4][4];
#pragma unroll
    for (int i = 0; i < 4; ++i)
#pragma unroll
      for (int j = 0; j < 4; ++j) acc[i][j] = 0.f;
#pragma unroll 4
    for (int d = 0; d < 64; ++d) {
      const float4 z4 = *(const float4*)&Zt[d][ty * 4];
      const float4 e4 = *(const float4*)&Et[d][tx * 4];
      acc[0][0] = fmaf(z4.x, e4.x, acc[0][0]);
      acc[0][1] = fmaf(z4.x, e4.y, acc[0][1]);
      acc[0][2] = fmaf(z4.x, e4.z, acc[0][2]);
      acc[0][3] = fmaf(z4.x, e4.w, acc[0][3]);
      acc[1][0] = fmaf(z4.y, e4.x, acc[1][0]);
      acc[1][1] = fmaf(z4.y, e4.y, acc[1][1]);
      acc[1][2] = fmaf(z4.y, e4.z, acc[1][2]);
      acc[1][3] = fmaf(z4.y, e4.w, acc[1][3]);
      acc[2][0] = fmaf(z4.z, e4.x, acc[2][0]);
      acc[2][1] = fmaf(z4.z, e4.y, acc[2][1]);
      acc[2][2] = fmaf(z4.z, e4.z, acc[2][2]);
      acc[2][3] = fmaf(z4.z, e4.w, acc[2][3]);
      acc[3][0] = fmaf(z4.w, e4.x, acc[3][0]);
      acc[3][1] = fmaf(z4.w, e4.y, acc[3][1]);
      acc[3][2] = fmaf(z4.w, e4.z, acc[3][2]);
      acc[3][3] = fmaf(z4.w, e4.w, acc[3][3]);
    }
    const float4 e2v = *(const float4*)&e2t[tx * 4];
    const int kb = k0 + tx * 4;
#pragma unroll
    for (int i = 0; i < 4; ++i) {
      float s0 = fmaf(-2.f, acc[i][0], e2v.x);
      float s1 = fmaf(-2.f, acc[i][1], e2v.y);
      float s2 = fmaf(-2.f, acc[i][2], e2v.z);
      float s3 = fmaf(-2.f, acc[i][3], e2v.w);
      if (s0 < mv[i]) { mv[i] = s0; mi[i] = kb; }
      if (s1 < mv[i]) { mv[i] = s1; mi[i] = kb + 1; }
      if (s2 < mv[i]) { mv[i] = s2; mi[i] = kb + 2; }
      if (s3 < mv[i]) { mv[i] = s3; mi[i] = kb + 3; }
    }
  }
  // reduce across the 16 tx lanes (contiguous within the wave)
#pragma unroll
  for (int off = 8; off >= 1; off >>= 1) {
#pragma unroll
    for (int i = 0; i < 4; ++i) {
      float ov = __shfl_xor(mv[i], off);
      int oi = __shfl_xor(mi[i], off);
      if (ov < mv[i] || (ov == mv[i] && oi < mi[i])) { mv[i] = ov; mi[i] = oi; }
    }
  }
  if (tx == 0) {
#pragma unroll
    for (int i = 0; i < 4; ++i) {
      int row = r0 + ty * 4 + i;
      pminv[kh * NROWS + row] = mv[i];
      pidx[kh * NROWS + row] = mi[i];
    }
  }
}

// ---------------- K3b: combine the two k-halves; emit final index (as float) to d_out tail
__global__ __launch_bounds__(256) void k_pick(const float* __restrict__ pminv,
                                              const int* __restrict__ pidx,
                                              float* __restrict__ idx_out) {
  int n = blockIdx.x * 256 + threadIdx.x;
  float v0 = pminv[n], v1 = pminv[NROWS + n];
  int i0 = pidx[n], i1 = pidx[NROWS + n];
  int best = (v1 < v0 || (v1 == v0 && i1 < i0)) ? i1 : i0;
  idx_out[n] = (float)best;
}

// ---------------- K4: decoder 1x1 conv from gathered codebook rows
__global__ __launch_bounds__(256) void k_dec(const float* __restrict__ emb,
                                             const float* __restrict__ w_out,
                                             const float* __restrict__ b_out,
                                             const float* __restrict__ idxf,
                                             float* __restrict__ out) {
  __shared__ float Qt[64][36];  // [d][w]
  __shared__ float Wt[64][68];  // [d][o]
  const int bh = blockIdx.x;
  const int b = bh >> 5, h = bh & 31;
  const int t = threadIdx.x;
  const int w = t & 31, og = t >> 5;
  const int ds = t & 63, rs = t >> 6;
#pragma unroll
  for (int i = 0; i < 8; ++i) {
    int r = rs + 4 * i;  // 0..31
    int qi = (int)idxf[bh * 32 + r];
    Qt[ds][r] = emb[(size_t)qi * DD + ds];
  }
  for (int ob = 0; ob < 8; ++ob) {
    const int o0 = ob * 64;
    __syncthreads();  // Qt staged (ob==0) / previous Wt consumed
#pragma unroll
    for (int i = 0; i < 16; ++i) {
      int oo = rs + 4 * i;
      Wt[ds][oo] = w_out[(size_t)(o0 + oo) * DD + ds];
    }
    __syncthreads();
    float a[8];
#pragma unroll
    for (int j = 0; j < 8; ++j) a[j] = b_out[o0 + og * 8 + j];
#pragma unroll 4
    for (int d = 0; d < 64; ++d) {
      float qv = Qt[d][w];
      const float4 w0 = *(const float4*)&Wt[d][og * 8];
      const float4 w1 = *(const float4*)&Wt[d][og * 8 + 4];
      a[0] = fmaf(qv, w0.x, a[0]);
      a[1] = fmaf(qv, w0.y, a[1]);
      a[2] = fmaf(qv, w0.z, a[2]);
      a[3] = fmaf(qv, w0.w, a[3]);
      a[4] = fmaf(qv, w1.x, a[4]);
      a[5] = fmaf(qv, w1.y, a[5]);
      a[6] = fmaf(qv, w1.z, a[6]);
      a[7] = fmaf(qv, w1.w, a[7]);
    }
    float* op = out + (((size_t)b * OUTC + o0 + og * 8) * HH + h) * WW + w;
#pragma unroll
    for (int j = 0; j < 8; ++j) op[(size_t)j * (HH * WW)] = a[j];
  }
}

extern "C" void kernel_launch(void* const* d_in, const int* in_sizes, int n_in,
                              void* d_out, int out_size, void* d_ws, size_t ws_size,
                              hipStream_t stream) {
  const float* x = (const float*)d_in[0];
  const float* w_in = (const float*)d_in[1];
  const float* b_in = (const float*)d_in[2];
  const float* emb = (const float*)d_in[3];
  const float* w_out = (const float*)d_in[4];
  const float* b_out = (const float*)d_in[5];
  float* out = (float*)d_out;

  // Scratch lives inside d_out's main region; k_dec overwrites it last.
  float* zf = out;                    // 1,048,576 floats (z flat [16384][64])
  float* e2 = out + 1048576;          // 8,192
  float* pminv = out + 1056768;       // 32,768 (2 x 16384)
  int* pidx = (int*)(out + 1089536);  // 32,768 ints
  float* idxf = out + OUT_MAIN;       // 16,384: final indices output (as float)

  k_enc<<<NB * HH, 256, 0, stream>>>(x, w_in, b_in, zf);
  k_e2<<<KK / 256, 256, 0, stream>>>(emb, e2);
  k_argmin<<<(NROWS / 64) * 2, 256, 0, stream>>>(zf, emb, e2, pminv, pidx);
  k_pick<<<NROWS / 256, 256, 0, stream>>>(pminv, pidx, idxf);
  k_dec<<<NB * HH, 256, 0, stream>>>(emb, w_out, b_out, idxf, out);
}